// Round 5
// baseline (84412.897 us; speedup 1.0000x reference)
//
#include <hip/hip_runtime.h>
#include <math.h>

// ESN recurrence: x_t = tanh(w_in*u_t + W x_{t-1}); out[t-washout] = c . x_t
// R5 = R4's contention-free chained barrier + fix of R4's correctness bug:
// the readout atomicAdd had been moved inside `if (wave==0)`, so only wave 0's
// two rows were summed into out (absmax 34). Readout is back to all waves'
// lane 0 (fire-and-forget, after wave 0's arrival add).
// Barrier: arrive = fetch_add chain (line counter -> global counter, the
// globally-last block knows inline), publish = 256 PRIVATE flag lines, each
// polled by exactly ONE wave. No fences; all cross-XCD words move via
// agent-scope relaxed atomics (write-through past the non-coherent L2s).

#define H_   2048
#define RPB  8          // rows per block
#define NBLK 256
// ws layout (floats):
//   [0,2048)        xbuf0
//   [2048,4096)     xbuf1
//   [4096,6144)     c (scatter of w_out by mask)
//   uint [6144,7168)  line counters: 32 lines x 32 uints (128 B stride)
//   uint [7168,7200)  global counter (1 line)
//   uint [8192,16384) flags: 256 private lines x 32 uints
//   [16384, 16384+T*32)  part accumulators: 32 spread slots per step

__global__ void esn_zero(float* __restrict__ p, int n)
{
    int i = blockIdx.x * blockDim.x + threadIdx.x;
    int stride = gridDim.x * blockDim.x;
    for (; i < n; i += stride) p[i] = 0.0f;
}

__global__ __launch_bounds__(1024) void esn_scatter_c(const int* __restrict__ mask,
                                                      const float* __restrict__ w_out,
                                                      float* __restrict__ ws_f, int H)
{
    float* c = ws_f + 2 * H_;
    for (int i = threadIdx.x; i < H; i += blockDim.x)
        atomicAdd(&c[mask[i]], w_out[i]);
}

__global__ __launch_bounds__(256) void esn_run(const float* __restrict__ u,
                                               const float* __restrict__ w_res,
                                               const float* __restrict__ w_in,
                                               float* __restrict__ out,
                                               float* __restrict__ ws_f,
                                               int T, int washout, int use_part)
{
    __shared__ float Wlds[RPB * H_];   // 64 KB
    __shared__ float xs[H_];           // 8 KB staged x_{t-1}

    const int tid  = threadIdx.x;
    const int wave = tid >> 6;
    const int lane = tid & 63;
    const int bid  = blockIdx.x;
    const int r0 = 2 * wave, r1 = 2 * wave + 1;
    const int grow0 = bid * RPB + r0, grow1 = bid * RPB + r1;

    // ---- one-time: stage this block's 8 W rows into LDS (coalesced) ----
    {
        const float4* src = (const float4*)(w_res + (size_t)bid * RPB * H_);
        float4* dst = (float4*)Wlds;
        for (int i = tid; i < RPB * H_ / 4; i += 256) dst[i] = src[i];
    }
    float win0 = 0.f, win1 = 0.f, c0 = 0.f, c1 = 0.f;
    if (lane == 0) {
        win0 = w_in[grow0]; win1 = w_in[grow1];
        c0 = ws_f[2 * H_ + grow0]; c1 = ws_f[2 * H_ + grow1];
    }

    float* buf0 = ws_f;
    float* buf1 = ws_f + H_;
    unsigned* linecnt = (unsigned*)(ws_f + 6144) + (bid & 31) * 32;
    unsigned* gcnt    = (unsigned*)(ws_f + 7168);
    unsigned* flags   = (unsigned*)(ws_f + 8192);
    unsigned* myflag  = flags + bid * 32;
    float* part = ws_f + 16384;
    const int pg = (bid & 7) * 4 + wave;   // 32 spread part slots per step

    const float4* w0p = (const float4*)(Wlds + r0 * H_);
    const float4* w1p = (const float4*)(Wlds + r1 * H_);
    const float4* xs4 = (const float4*)xs;

    int broken = 0;
    float u_next = u[0];
    __syncthreads();   // Wlds ready

    for (int k = 0; k < T; ++k) {
        // ---- stage x_{t-1} from L3 into LDS (agent-scope relaxed loads) ----
        const float* xsrc = (k & 1) ? buf1 : buf0;
        float*       xdst = (k & 1) ? buf0 : buf1;
#pragma unroll
        for (int i = 0; i < 8; ++i) {
            int j = (i << 8) + tid;
            xs[j] = __hip_atomic_load(xsrc + j, __ATOMIC_RELAXED,
                                      __HIP_MEMORY_SCOPE_AGENT);
        }
        float uk = u_next;
        if (k + 1 < T) u_next = u[k + 1];
        __syncthreads();

        // ---- dot: wave owns rows r0,r1; lanes sweep 2048 as float4 ----
        float4 a0 = {0.f, 0.f, 0.f, 0.f}, a1 = {0.f, 0.f, 0.f, 0.f};
#pragma unroll
        for (int c = 0; c < 8; ++c) {
            float4 xv  = xs4[c * 64 + lane];
            float4 wv0 = w0p[c * 64 + lane];
            float4 wv1 = w1p[c * 64 + lane];
            a0.x = fmaf(wv0.x, xv.x, a0.x); a0.y = fmaf(wv0.y, xv.y, a0.y);
            a0.z = fmaf(wv0.z, xv.z, a0.z); a0.w = fmaf(wv0.w, xv.w, a0.w);
            a1.x = fmaf(wv1.x, xv.x, a1.x); a1.y = fmaf(wv1.y, xv.y, a1.y);
            a1.z = fmaf(wv1.z, xv.z, a1.z); a1.w = fmaf(wv1.w, xv.w, a1.w);
        }
        float s0 = (a0.x + a0.y) + (a0.z + a0.w);
        float s1 = (a1.x + a1.y) + (a1.z + a1.w);
#pragma unroll
        for (int d = 1; d < 64; d <<= 1) {
            s0 += __shfl_xor(s0, d);
            s1 += __shfl_xor(s1, d);
        }

        float pw = 0.f;
        if (lane == 0) {
            float z0 = fmaf(win0, uk, s0);
            float z1 = fmaf(win1, uk, s1);
            z0 = fminf(fmaxf(z0, -15.f), 15.f);
            z1 = fminf(fmaxf(z1, -15.f), 15.f);
            float e0 = __expf(2.f * z0), e1 = __expf(2.f * z1);
            float t0 = (e0 - 1.f) / (e0 + 1.f), t1 = (e1 - 1.f) / (e1 + 1.f);
            __hip_atomic_store(xdst + grow0, t0, __ATOMIC_RELAXED,
                               __HIP_MEMORY_SCOPE_AGENT);
            __hip_atomic_store(xdst + grow1, t1, __ATOMIC_RELAXED,
                               __HIP_MEMORY_SCOPE_AGENT);
            pw = c0 * t0 + c1 * t1;
        }
        asm volatile("s_waitcnt vmcnt(0)" ::: "memory");  // x stores at L3
        __syncthreads();                                  // all waves drained

        // ---- arrival: wave 0 lane 0 only ----
        int pub = 0;
        if (wave == 0 && lane == 0) {
            unsigned old = __hip_atomic_fetch_add(linecnt, 1u, __ATOMIC_RELAXED,
                                                  __HIP_MEMORY_SCOPE_AGENT);
            if (old + 1u == (unsigned)(k + 1) * 8u) {       // last on my line
                unsigned g = __hip_atomic_fetch_add(gcnt, 1u, __ATOMIC_RELAXED,
                                                    __HIP_MEMORY_SCOPE_AGENT);
                if (g + 1u == (unsigned)(k + 1) * 32u) pub = 1;  // global last
            }
        }
        // ---- readout: EVERY wave's lane 0 (R4 bug: this was wave-0-only) ----
        if (lane == 0 && k >= washout) {
            if (use_part) atomicAdd(&part[(size_t)k * 32 + pg], pw);
            else          atomicAdd(&out[k - washout], pw);
        }

        // ---- publish / wait (wave 0 only) ----
        if (wave == 0) {
            pub = __shfl(pub, 0);
            if (pub) {
                // publish epoch to all 256 private flag lines (incl. our own)
#pragma unroll
                for (int i = 0; i < 4; ++i)
                    __hip_atomic_store(flags + (i * 64 + lane) * 32,
                                       (unsigned)(k + 1), __ATOMIC_RELAXED,
                                       __HIP_MEMORY_SCOPE_AGENT);
            } else if (!broken) {
                // single poller on a private line: zero contention
                unsigned target = (unsigned)(k + 1);
                int spins = 0;
                for (;;) {
                    unsigned v = __hip_atomic_load(myflag, __ATOMIC_RELAXED,
                                                   __HIP_MEMORY_SCOPE_AGENT);
                    if (v >= target) break;
                    if (++spins > 1000000) { broken = 1; break; }
                }
            }
        }
        __syncthreads();
    }
}

__global__ void esn_reduce(const float* __restrict__ part, float* __restrict__ out,
                           int out_size, int washout)
{
    int t = blockIdx.x * blockDim.x + threadIdx.x;
    if (t >= out_size) return;
    const float* p = part + (size_t)(t + washout) * 32;
    float s = 0.f;
#pragma unroll
    for (int g = 0; g < 32; ++g) s += p[g];
    out[t] = s;
}

extern "C" void kernel_launch(void* const* d_in, const int* in_sizes, int n_in,
                              void* d_out, int out_size, void* d_ws, size_t ws_size,
                              hipStream_t stream)
{
    const float* u     = (const float*)d_in[0];
    const float* w_res = (const float*)d_in[1];
    const float* w_in  = (const float*)d_in[2];
    const float* w_out = (const float*)d_in[3];
    const int*   mask  = (const int*)d_in[4];
    int T = in_sizes[0];
    int H = in_sizes[2];
    int washout = T - out_size;
    float* out  = (float*)d_out;
    float* ws_f = (float*)d_ws;

    size_t need = (size_t)(16384 + (size_t)T * 32) * 4;
    int use_part = (ws_size >= need) ? 1 : 0;
    int zero_n = use_part ? (16384 + T * 32) : 16384;

    hipLaunchKernelGGL(esn_zero, dim3(64), dim3(256), 0, stream, ws_f, zero_n);
    if (!use_part)
        hipLaunchKernelGGL(esn_zero, dim3(32), dim3(256), 0, stream, out, out_size);
    hipLaunchKernelGGL(esn_scatter_c, dim3(1), dim3(1024), 0, stream, mask, w_out, ws_f, H);

    void* args[] = { (void*)&u, (void*)&w_res, (void*)&w_in, (void*)&out,
                     (void*)&ws_f, (void*)&T, (void*)&washout, (void*)&use_part };
    hipError_t e = hipLaunchCooperativeKernel((const void*)esn_run,
                                              dim3(NBLK), dim3(256),
                                              args, 0, stream);
    if (e != hipSuccess) {
        hipLaunchKernelGGL(esn_run, dim3(NBLK), dim3(256), 0, stream,
                           u, w_res, w_in, out, ws_f, T, washout, use_part);
    }
    if (use_part)
        hipLaunchKernelGGL(esn_reduce, dim3((out_size + 255) / 256), dim3(256), 0, stream,
                           ws_f + 16384, out, out_size, washout);
}